// Round 1
// baseline (809.271 us; speedup 1.0000x reference)
//
#include <hip/hip_runtime.h>

#define IN_F 128
#define H 64

// ---------------- degree / normalization ----------------

__global__ void count_deg(const int* __restrict__ col, int* __restrict__ cnt, int E) {
    int e = blockIdx.x * 256 + threadIdx.x;
    if (e < E) atomicAdd(&cnt[col[e]], 1);
}

__global__ void calc_dis(const int* __restrict__ cnt, float* __restrict__ dis, int N) {
    int i = blockIdx.x * 256 + threadIdx.x;
    if (i < N) dis[i] = rsqrtf((float)(cnt[i] + 1));  // +1 self-loop; deg>=1 always
}

// ---------------- exclusive scan of cnt -> offs ----------------

__global__ void scan1(const int* __restrict__ cnt, int* __restrict__ bsum, int N) {
    __shared__ int s[1024];
    int t = threadIdx.x;
    int i = blockIdx.x * 1024 + t;
    s[t] = (i < N) ? cnt[i] : 0;
    __syncthreads();
    for (int off = 512; off > 0; off >>= 1) {
        if (t < off) s[t] += s[t + off];
        __syncthreads();
    }
    if (t == 0) bsum[blockIdx.x] = s[0];
}

// single-block exclusive scan of block sums (nb <= 128)
__global__ void scan2(int* bsum, int nb) {
    __shared__ int s[128];
    int t = threadIdx.x;
    int v = (t < nb) ? bsum[t] : 0;
    s[t] = v;
    __syncthreads();
    for (int off = 1; off < 128; off <<= 1) {
        int tmp = (t >= off) ? s[t - off] : 0;
        __syncthreads();
        s[t] += tmp;
        __syncthreads();
    }
    if (t < nb) bsum[t] = s[t] - v;  // exclusive
}

__global__ void scan3(const int* __restrict__ cnt, const int* __restrict__ bsum,
                      int* __restrict__ offs, int N) {
    __shared__ int s[1024];
    int t = threadIdx.x;
    int i = blockIdx.x * 1024 + t;
    int v = (i < N) ? cnt[i] : 0;
    s[t] = v;
    __syncthreads();
    for (int off = 1; off < 1024; off <<= 1) {
        int tmp = (t >= off) ? s[t - off] : 0;
        __syncthreads();
        s[t] += tmp;
        __syncthreads();
    }
    if (i < N) offs[i] = bsum[blockIdx.x] + s[t] - v;       // exclusive prefix
    if (i == N - 1) offs[N] = bsum[blockIdx.x] + s[t];      // == E
}

// ---------------- CSR fill (col-sorted adjacency) ----------------

__global__ void fill_csr(const int* __restrict__ row, const int* __restrict__ col,
                         const float* __restrict__ dis, const int* __restrict__ offs,
                         int* __restrict__ cursor, int* __restrict__ src,
                         float* __restrict__ nrm, int E) {
    int e = blockIdx.x * 256 + threadIdx.x;
    if (e >= E) return;
    int r = row[e], c = col[e];
    int p = atomicAdd(&cursor[c], 1);
    int idx = offs[c] + p;
    src[idx] = r;
    nrm[idx] = dis[r] * dis[c];
}

// ---------------- dense GEMMs ----------------

// out[N,64] = x[N,128] @ W[128,64].  16 rows/block, 256 thr (64 cols x 4 row-groups),
// 4 rows/thread.
__global__ void mm1(const float* __restrict__ x, const float* __restrict__ W,
                    float* __restrict__ out, int N) {
    __shared__ float Wl[IN_F * H];
    int t = threadIdx.x;
    for (int i = t; i < IN_F * H; i += 256) Wl[i] = W[i];
    __syncthreads();
    int c = t & 63, rq = t >> 6;
    int r0 = blockIdx.x * 16 + rq * 4;
    if (r0 >= N) return;
    float a0 = 0, a1 = 0, a2 = 0, a3 = 0;
    const float* x0 = x + (size_t)r0 * IN_F;
    for (int k = 0; k < IN_F; k += 4) {
        float4 v0 = *(const float4*)(x0 + k);
        float4 v1 = *(const float4*)(x0 + IN_F + k);
        float4 v2 = *(const float4*)(x0 + 2 * IN_F + k);
        float4 v3 = *(const float4*)(x0 + 3 * IN_F + k);
        float w0 = Wl[k * H + c], w1 = Wl[(k + 1) * H + c];
        float w2 = Wl[(k + 2) * H + c], w3 = Wl[(k + 3) * H + c];
        a0 += v0.x * w0 + v0.y * w1 + v0.z * w2 + v0.w * w3;
        a1 += v1.x * w0 + v1.y * w1 + v1.z * w2 + v1.w * w3;
        a2 += v2.x * w0 + v2.y * w1 + v2.z * w2 + v2.w * w3;
        a3 += v3.x * w0 + v3.y * w1 + v3.z * w2 + v3.w * w3;
    }
    float* o = out + (size_t)r0 * H + c;
    o[0] = a0; o[H] = a1; o[2 * H] = a2; o[3 * H] = a3;
}

// out[N,64] = relu(hin[N,64] + b) @ W[64,64]   (bias+relu fused into load)
__global__ void mm2(const float* __restrict__ hin, const float* __restrict__ b,
                    const float* __restrict__ W, float* __restrict__ out, int N) {
    __shared__ float Wl[H * H];
    __shared__ float bl[H];
    int t = threadIdx.x;
    for (int i = t; i < H * H; i += 256) Wl[i] = W[i];
    if (t < H) bl[t] = b[t];
    __syncthreads();
    int c = t & 63, rq = t >> 6;
    int r0 = blockIdx.x * 16 + rq * 4;
    if (r0 >= N) return;
    float a0 = 0, a1 = 0, a2 = 0, a3 = 0;
    const float* h0 = hin + (size_t)r0 * H;
    for (int k = 0; k < H; k += 4) {
        float4 v0 = *(const float4*)(h0 + k);
        float4 v1 = *(const float4*)(h0 + H + k);
        float4 v2 = *(const float4*)(h0 + 2 * H + k);
        float4 v3 = *(const float4*)(h0 + 3 * H + k);
        float bb0 = bl[k], bb1 = bl[k + 1], bb2 = bl[k + 2], bb3 = bl[k + 3];
        v0.x = fmaxf(v0.x + bb0, 0.f); v0.y = fmaxf(v0.y + bb1, 0.f);
        v0.z = fmaxf(v0.z + bb2, 0.f); v0.w = fmaxf(v0.w + bb3, 0.f);
        v1.x = fmaxf(v1.x + bb0, 0.f); v1.y = fmaxf(v1.y + bb1, 0.f);
        v1.z = fmaxf(v1.z + bb2, 0.f); v1.w = fmaxf(v1.w + bb3, 0.f);
        v2.x = fmaxf(v2.x + bb0, 0.f); v2.y = fmaxf(v2.y + bb1, 0.f);
        v2.z = fmaxf(v2.z + bb2, 0.f); v2.w = fmaxf(v2.w + bb3, 0.f);
        v3.x = fmaxf(v3.x + bb0, 0.f); v3.y = fmaxf(v3.y + bb1, 0.f);
        v3.z = fmaxf(v3.z + bb2, 0.f); v3.w = fmaxf(v3.w + bb3, 0.f);
        float w0 = Wl[k * H + c], w1 = Wl[(k + 1) * H + c];
        float w2 = Wl[(k + 2) * H + c], w3 = Wl[(k + 3) * H + c];
        a0 += v0.x * w0 + v0.y * w1 + v0.z * w2 + v0.w * w3;
        a1 += v1.x * w0 + v1.y * w1 + v1.z * w2 + v1.w * w3;
        a2 += v2.x * w0 + v2.y * w1 + v2.z * w2 + v2.w * w3;
        a3 += v3.x * w0 + v3.y * w1 + v3.z * w2 + v3.w * w3;
    }
    float* o = out + (size_t)r0 * H + c;
    o[0] = a0; o[H] = a1; o[2 * H] = a2; o[3 * H] = a3;
}

// out[N,4] = (hin[N,64] + b) @ W[64,4]   (bias fused, no relu)
__global__ void mm3(const float* __restrict__ hin, const float* __restrict__ b,
                    const float* __restrict__ W, float* __restrict__ out, int N) {
    __shared__ float Wl[H * 4];
    __shared__ float bl[H];
    int t = threadIdx.x;
    if (t < H * 4) Wl[t] = W[t];
    if (t < H) bl[t] = b[t];
    __syncthreads();
    int c = t & 3, rr = t >> 2;
    int r = blockIdx.x * 64 + rr;
    if (r >= N) return;
    const float* h0 = hin + (size_t)r * H;
    float a = 0;
    for (int k = 0; k < H; k += 4) {
        float4 v = *(const float4*)(h0 + k);
        a += (v.x + bl[k])     * Wl[k * 4 + c];
        a += (v.y + bl[k + 1]) * Wl[(k + 1) * 4 + c];
        a += (v.z + bl[k + 2]) * Wl[(k + 2) * 4 + c];
        a += (v.w + bl[k + 3]) * Wl[(k + 3) * 4 + c];
    }
    out[(size_t)r * 4 + c] = a;
}

// ---------------- aggregation (gather over CSR) ----------------

// one wave per node, lane = feature (64 features)
__global__ void agg64(const float* __restrict__ xw, const int* __restrict__ offs,
                      const int* __restrict__ src, const float* __restrict__ nrm,
                      const float* __restrict__ dis, float* __restrict__ out, int N) {
    int wid = (blockIdx.x * 256 + threadIdx.x) >> 6;
    int lane = threadIdx.x & 63;
    if (wid >= N) return;
    int beg = offs[wid], end = offs[wid + 1];
    float d = dis[wid];
    float acc = d * d * xw[(size_t)wid * 64 + lane];  // self-loop term
    int j = beg;
    for (; j + 4 <= end; j += 4) {
        int s0 = src[j], s1 = src[j + 1], s2 = src[j + 2], s3 = src[j + 3];
        float w0 = nrm[j], w1 = nrm[j + 1], w2 = nrm[j + 2], w3 = nrm[j + 3];
        acc += w0 * xw[(size_t)s0 * 64 + lane];
        acc += w1 * xw[(size_t)s1 * 64 + lane];
        acc += w2 * xw[(size_t)s2 * 64 + lane];
        acc += w3 * xw[(size_t)s3 * 64 + lane];
    }
    for (; j < end; ++j) acc += nrm[j] * xw[(size_t)src[j] * 64 + lane];
    out[(size_t)wid * 64 + lane] = acc;
}

// one thread per node, 4 features in a float4; writes final output (+b3)
__global__ void agg4(const float* __restrict__ xw, const int* __restrict__ offs,
                     const int* __restrict__ src, const float* __restrict__ nrm,
                     const float* __restrict__ dis, const float* __restrict__ b,
                     float* __restrict__ out, int N) {
    int i = blockIdx.x * 256 + threadIdx.x;
    if (i >= N) return;
    float d = dis[i];
    float4 v = *(const float4*)(xw + (size_t)i * 4);
    float4 acc;
    acc.x = b[0] + d * d * v.x;
    acc.y = b[1] + d * d * v.y;
    acc.z = b[2] + d * d * v.z;
    acc.w = b[3] + d * d * v.w;
    int beg = offs[i], end = offs[i + 1];
    for (int j = beg; j < end; ++j) {
        float w = nrm[j];
        float4 m = *(const float4*)(xw + (size_t)src[j] * 4);
        acc.x += w * m.x; acc.y += w * m.y; acc.z += w * m.z; acc.w += w * m.w;
    }
    *(float4*)(out + (size_t)i * 4) = acc;
}

// ---------------- host ----------------

extern "C" void kernel_launch(void* const* d_in, const int* in_sizes, int n_in,
                              void* d_out, int out_size, void* d_ws, size_t ws_size,
                              hipStream_t stream) {
    const float* x  = (const float*)d_in[0];
    const int*   ei = (const int*)d_in[1];
    const float* W1 = (const float*)d_in[2];
    const float* b1 = (const float*)d_in[3];
    const float* W2 = (const float*)d_in[4];
    const float* b2 = (const float*)d_in[5];
    const float* W3 = (const float*)d_in[6];
    const float* b3 = (const float*)d_in[7];
    float* out = (float*)d_out;
    (void)n_in; (void)out_size; (void)ws_size;

    const int N = in_sizes[0] / IN_F;
    const int E = in_sizes[1] / 2;
    const int* row = ei;
    const int* col = ei + E;

    // workspace carve (all 256B-aligned)
    char* w = (char*)d_ws;
    auto carve = [&](size_t bytes) { char* p = w; w += (bytes + 255) & ~(size_t)255; return p; };
    float* bufA   = (float*)carve((size_t)N * H * 4);   // 25.6 MB
    float* bufB   = (float*)carve((size_t)N * H * 4);   // 25.6 MB
    float* bufC   = (float*)carve((size_t)N * 4 * 4);   // 1.6 MB
    float* dis    = (float*)carve((size_t)N * 4);
    int*   cnt    = (int*)carve((size_t)N * 4);
    int*   offs   = (int*)carve((size_t)(N + 1) * 4);
    int*   cursor = (int*)carve((size_t)N * 4);
    int*   bsum   = (int*)carve(4096);
    int*   srcb   = (int*)carve((size_t)E * 4);         // 12.8 MB
    float* nrmb   = (float*)carve((size_t)E * 4);       // 12.8 MB

    hipMemsetAsync(cnt, 0, (size_t)N * 4, stream);
    hipMemsetAsync(cursor, 0, (size_t)N * 4, stream);

    int gE = (E + 255) / 256;
    int gN = (N + 255) / 256;
    int nb = (N + 1023) / 1024;  // 98 <= 128

    count_deg<<<gE, 256, 0, stream>>>(col, cnt, E);
    calc_dis<<<gN, 256, 0, stream>>>(cnt, dis, N);

    scan1<<<nb, 1024, 0, stream>>>(cnt, bsum, N);
    scan2<<<1, 128, 0, stream>>>(bsum, nb);
    scan3<<<nb, 1024, 0, stream>>>(cnt, bsum, offs, N);

    fill_csr<<<gE, 256, 0, stream>>>(row, col, dis, offs, cursor, srcb, nrmb, E);

    // layer 1: xw = x@W1 ; agg ; (bias+relu deferred into mm2 loads)
    mm1<<<(N + 15) / 16, 256, 0, stream>>>(x, W1, bufA, N);
    agg64<<<(N + 3) / 4, 256, 0, stream>>>(bufA, offs, srcb, nrmb, dis, bufB, N);
    // layer 2: xw = relu(agg1+b1)@W2 ; agg ; (bias deferred into mm3 loads)
    mm2<<<(N + 15) / 16, 256, 0, stream>>>(bufB, b1, W2, bufA, N);
    agg64<<<(N + 3) / 4, 256, 0, stream>>>(bufA, offs, srcb, nrmb, dis, bufB, N);
    // layer 3: xw = (agg2+b2)@W3 ; agg (+b3) -> out
    mm3<<<(N + 63) / 64, 256, 0, stream>>>(bufB, b2, W3, bufC, N);
    agg4<<<gN, 256, 0, stream>>>(bufC, offs, srcb, nrmb, dis, b3, out, N);
}

// Round 2
// 656.157 us; speedup vs baseline: 1.2333x; 1.2333x over previous
//
#include <hip/hip_runtime.h>

#define IN_F 128
#define H 64

// ---------------- degree + per-edge rank (one atomic pass) ----------------

__global__ void count_rank(const int* __restrict__ col, int* __restrict__ cnt,
                           int* __restrict__ rank, int E) {
    int e = blockIdx.x * 256 + threadIdx.x;
    if (e < E) rank[e] = atomicAdd(&cnt[col[e]], 1);
}

__global__ void calc_dis(const int* __restrict__ cnt, float* __restrict__ dis, int N) {
    int i = blockIdx.x * 256 + threadIdx.x;
    if (i < N) dis[i] = rsqrtf((float)(cnt[i] + 1));  // +1 self-loop; deg>=1 always
}

// ---------------- exclusive scan of cnt -> offs ----------------

__global__ void scan1(const int* __restrict__ cnt, int* __restrict__ bsum, int N) {
    __shared__ int s[1024];
    int t = threadIdx.x;
    int i = blockIdx.x * 1024 + t;
    s[t] = (i < N) ? cnt[i] : 0;
    __syncthreads();
    for (int off = 512; off > 0; off >>= 1) {
        if (t < off) s[t] += s[t + off];
        __syncthreads();
    }
    if (t == 0) bsum[blockIdx.x] = s[0];
}

// single-block exclusive scan of block sums (nb <= 128)
__global__ void scan2(int* bsum, int nb) {
    __shared__ int s[128];
    int t = threadIdx.x;
    int v = (t < nb) ? bsum[t] : 0;
    s[t] = v;
    __syncthreads();
    for (int off = 1; off < 128; off <<= 1) {
        int tmp = (t >= off) ? s[t - off] : 0;
        __syncthreads();
        s[t] += tmp;
        __syncthreads();
    }
    if (t < nb) bsum[t] = s[t] - v;  // exclusive
}

__global__ void scan3(const int* __restrict__ cnt, const int* __restrict__ bsum,
                      int* __restrict__ offs, int N) {
    __shared__ int s[1024];
    int t = threadIdx.x;
    int i = blockIdx.x * 1024 + t;
    int v = (i < N) ? cnt[i] : 0;
    s[t] = v;
    __syncthreads();
    for (int off = 1; off < 1024; off <<= 1) {
        int tmp = (t >= off) ? s[t - off] : 0;
        __syncthreads();
        s[t] += tmp;
        __syncthreads();
    }
    if (i < N) offs[i] = bsum[blockIdx.x] + s[t] - v;       // exclusive prefix
    if (i == N - 1) offs[N] = bsum[blockIdx.x] + s[t];      // == E
}

// ---------------- CSR fill (col-sorted adjacency), atomic-free ----------------

__global__ void fill_src(const int* __restrict__ row, const int* __restrict__ col,
                         const int* __restrict__ rank, const int* __restrict__ offs,
                         int* __restrict__ src, int E) {
    int e = blockIdx.x * 256 + threadIdx.x;
    if (e >= E) return;
    int idx = offs[col[e]] + rank[e];
    __builtin_nontemporal_store(row[e], &src[idx]);
}

// ---------------- dense GEMMs (store pre-scaled by dis[r]) ----------------

// out[r,:] = dis[r] * (x[r,:] @ W)    x:[N,128] W:[128,64]
__global__ void mm1(const float* __restrict__ x, const float* __restrict__ W,
                    const float* __restrict__ dis, float* __restrict__ out, int N) {
    __shared__ float Wl[IN_F * H];
    int t = threadIdx.x;
    for (int i = t; i < IN_F * H; i += 256) Wl[i] = W[i];
    __syncthreads();
    int c = t & 63, rq = t >> 6;
    int r0 = blockIdx.x * 16 + rq * 4;
    if (r0 >= N) return;
    float a0 = 0, a1 = 0, a2 = 0, a3 = 0;
    const float* x0 = x + (size_t)r0 * IN_F;
    for (int k = 0; k < IN_F; k += 4) {
        float4 v0 = *(const float4*)(x0 + k);
        float4 v1 = *(const float4*)(x0 + IN_F + k);
        float4 v2 = *(const float4*)(x0 + 2 * IN_F + k);
        float4 v3 = *(const float4*)(x0 + 3 * IN_F + k);
        float w0 = Wl[k * H + c], w1 = Wl[(k + 1) * H + c];
        float w2 = Wl[(k + 2) * H + c], w3 = Wl[(k + 3) * H + c];
        a0 += v0.x * w0 + v0.y * w1 + v0.z * w2 + v0.w * w3;
        a1 += v1.x * w0 + v1.y * w1 + v1.z * w2 + v1.w * w3;
        a2 += v2.x * w0 + v2.y * w1 + v2.z * w2 + v2.w * w3;
        a3 += v3.x * w0 + v3.y * w1 + v3.z * w2 + v3.w * w3;
    }
    float* o = out + (size_t)r0 * H + c;
    o[0]     = dis[r0]     * a0;
    o[H]     = dis[r0 + 1] * a1;
    o[2 * H] = dis[r0 + 2] * a2;
    o[3 * H] = dis[r0 + 3] * a3;
}

// out[r,:] = dis[r] * (relu(hin[r,:] + b) @ W)   (bias+relu fused into load)
__global__ void mm2(const float* __restrict__ hin, const float* __restrict__ b,
                    const float* __restrict__ W, const float* __restrict__ dis,
                    float* __restrict__ out, int N) {
    __shared__ float Wl[H * H];
    __shared__ float bl[H];
    int t = threadIdx.x;
    for (int i = t; i < H * H; i += 256) Wl[i] = W[i];
    if (t < H) bl[t] = b[t];
    __syncthreads();
    int c = t & 63, rq = t >> 6;
    int r0 = blockIdx.x * 16 + rq * 4;
    if (r0 >= N) return;
    float a0 = 0, a1 = 0, a2 = 0, a3 = 0;
    const float* h0 = hin + (size_t)r0 * H;
    for (int k = 0; k < H; k += 4) {
        float4 v0 = *(const float4*)(h0 + k);
        float4 v1 = *(const float4*)(h0 + H + k);
        float4 v2 = *(const float4*)(h0 + 2 * H + k);
        float4 v3 = *(const float4*)(h0 + 3 * H + k);
        float bb0 = bl[k], bb1 = bl[k + 1], bb2 = bl[k + 2], bb3 = bl[k + 3];
        v0.x = fmaxf(v0.x + bb0, 0.f); v0.y = fmaxf(v0.y + bb1, 0.f);
        v0.z = fmaxf(v0.z + bb2, 0.f); v0.w = fmaxf(v0.w + bb3, 0.f);
        v1.x = fmaxf(v1.x + bb0, 0.f); v1.y = fmaxf(v1.y + bb1, 0.f);
        v1.z = fmaxf(v1.z + bb2, 0.f); v1.w = fmaxf(v1.w + bb3, 0.f);
        v2.x = fmaxf(v2.x + bb0, 0.f); v2.y = fmaxf(v2.y + bb1, 0.f);
        v2.z = fmaxf(v2.z + bb2, 0.f); v2.w = fmaxf(v2.w + bb3, 0.f);
        v3.x = fmaxf(v3.x + bb0, 0.f); v3.y = fmaxf(v3.y + bb1, 0.f);
        v3.z = fmaxf(v3.z + bb2, 0.f); v3.w = fmaxf(v3.w + bb3, 0.f);
        float w0 = Wl[k * H + c], w1 = Wl[(k + 1) * H + c];
        float w2 = Wl[(k + 2) * H + c], w3 = Wl[(k + 3) * H + c];
        a0 += v0.x * w0 + v0.y * w1 + v0.z * w2 + v0.w * w3;
        a1 += v1.x * w0 + v1.y * w1 + v1.z * w2 + v1.w * w3;
        a2 += v2.x * w0 + v2.y * w1 + v2.z * w2 + v2.w * w3;
        a3 += v3.x * w0 + v3.y * w1 + v3.z * w2 + v3.w * w3;
    }
    float* o = out + (size_t)r0 * H + c;
    o[0]     = dis[r0]     * a0;
    o[H]     = dis[r0 + 1] * a1;
    o[2 * H] = dis[r0 + 2] * a2;
    o[3 * H] = dis[r0 + 3] * a3;
}

// out[r,:] = dis[r] * ((hin[r,:] + b) @ W)   W:[64,4]  (bias fused, no relu)
__global__ void mm3(const float* __restrict__ hin, const float* __restrict__ b,
                    const float* __restrict__ W, const float* __restrict__ dis,
                    float* __restrict__ out, int N) {
    __shared__ float Wl[H * 4];
    __shared__ float bl[H];
    int t = threadIdx.x;
    if (t < H * 4) Wl[t] = W[t];
    if (t < H) bl[t] = b[t];
    __syncthreads();
    int c = t & 3, rr = t >> 2;
    int r = blockIdx.x * 64 + rr;
    if (r >= N) return;
    const float* h0 = hin + (size_t)r * H;
    float a = 0;
    for (int k = 0; k < H; k += 4) {
        float4 v = *(const float4*)(h0 + k);
        a += (v.x + bl[k])     * Wl[k * 4 + c];
        a += (v.y + bl[k + 1]) * Wl[(k + 1) * 4 + c];
        a += (v.z + bl[k + 2]) * Wl[(k + 2) * 4 + c];
        a += (v.w + bl[k + 3]) * Wl[(k + 3) * 4 + c];
    }
    out[(size_t)r * 4 + c] = dis[r] * a;
}

// ---------------- aggregation (gather over CSR, weight-free inner loop) ----------------

// one wave per node, lane = feature. out[c,:] = dis[c] * (xs[c,:] + sum_src xs[src,:])
__global__ void agg64(const float* __restrict__ xs, const int* __restrict__ offs,
                      const int* __restrict__ src, const float* __restrict__ dis,
                      float* __restrict__ out, int N) {
    int wid = (blockIdx.x * 256 + threadIdx.x) >> 6;
    int lane = threadIdx.x & 63;
    if (wid >= N) return;
    int beg = offs[wid], end = offs[wid + 1];
    float acc = xs[(size_t)wid * 64 + lane];  // self-loop term (pre-scaled)
    int j = beg;
    for (; j + 8 <= end; j += 8) {
        int s0 = src[j], s1 = src[j + 1], s2 = src[j + 2], s3 = src[j + 3];
        int s4 = src[j + 4], s5 = src[j + 5], s6 = src[j + 6], s7 = src[j + 7];
        float v0 = xs[(size_t)s0 * 64 + lane];
        float v1 = xs[(size_t)s1 * 64 + lane];
        float v2 = xs[(size_t)s2 * 64 + lane];
        float v3 = xs[(size_t)s3 * 64 + lane];
        float v4 = xs[(size_t)s4 * 64 + lane];
        float v5 = xs[(size_t)s5 * 64 + lane];
        float v6 = xs[(size_t)s6 * 64 + lane];
        float v7 = xs[(size_t)s7 * 64 + lane];
        acc += v0; acc += v1; acc += v2; acc += v3;
        acc += v4; acc += v5; acc += v6; acc += v7;
    }
    for (; j < end; ++j) acc += xs[(size_t)src[j] * 64 + lane];
    out[(size_t)wid * 64 + lane] = dis[wid] * acc;
}

// one thread per node, 4 features; writes final output: dis[c]*(inner) + b3
__global__ void agg4(const float* __restrict__ xs, const int* __restrict__ offs,
                     const int* __restrict__ src, const float* __restrict__ dis,
                     const float* __restrict__ b, float* __restrict__ out, int N) {
    int i = blockIdx.x * 256 + threadIdx.x;
    if (i >= N) return;
    float4 v = *(const float4*)(xs + (size_t)i * 4);
    float4 acc = v;  // self-loop term
    int beg = offs[i], end = offs[i + 1];
    for (int j = beg; j < end; ++j) {
        float4 m = *(const float4*)(xs + (size_t)src[j] * 4);
        acc.x += m.x; acc.y += m.y; acc.z += m.z; acc.w += m.w;
    }
    float d = dis[i];
    float4 o;
    o.x = b[0] + d * acc.x;
    o.y = b[1] + d * acc.y;
    o.z = b[2] + d * acc.z;
    o.w = b[3] + d * acc.w;
    *(float4*)(out + (size_t)i * 4) = o;
}

// ---------------- host ----------------

extern "C" void kernel_launch(void* const* d_in, const int* in_sizes, int n_in,
                              void* d_out, int out_size, void* d_ws, size_t ws_size,
                              hipStream_t stream) {
    const float* x  = (const float*)d_in[0];
    const int*   ei = (const int*)d_in[1];
    const float* W1 = (const float*)d_in[2];
    const float* b1 = (const float*)d_in[3];
    const float* W2 = (const float*)d_in[4];
    const float* b2 = (const float*)d_in[5];
    const float* W3 = (const float*)d_in[6];
    const float* b3 = (const float*)d_in[7];
    float* out = (float*)d_out;
    (void)n_in; (void)out_size; (void)ws_size;

    const int N = in_sizes[0] / IN_F;
    const int E = in_sizes[1] / 2;
    const int* row = ei;
    const int* col = ei + E;

    // workspace carve (all 256B-aligned)
    char* w = (char*)d_ws;
    auto carve = [&](size_t bytes) { char* p = w; w += (bytes + 255) & ~(size_t)255; return p; };
    float* bufA = (float*)carve((size_t)N * H * 4);   // 25.6 MB
    float* bufB = (float*)carve((size_t)N * H * 4);   // 25.6 MB
    float* bufC = (float*)carve((size_t)N * 4 * 4);   // 1.6 MB
    float* dis  = (float*)carve((size_t)N * 4);
    int*   cnt  = (int*)carve((size_t)N * 4);
    int*   offs = (int*)carve((size_t)(N + 1) * 4);
    int*   bsum = (int*)carve(4096);
    int*   rank = (int*)carve((size_t)E * 4);         // 12.8 MB
    int*   srcb = (int*)carve((size_t)E * 4);         // 12.8 MB

    hipMemsetAsync(cnt, 0, (size_t)N * 4, stream);

    int gE = (E + 255) / 256;
    int gN = (N + 255) / 256;
    int nb = (N + 1023) / 1024;  // 98 <= 128

    count_rank<<<gE, 256, 0, stream>>>(col, cnt, rank, E);
    calc_dis<<<gN, 256, 0, stream>>>(cnt, dis, N);

    scan1<<<nb, 1024, 0, stream>>>(cnt, bsum, N);
    scan2<<<1, 128, 0, stream>>>(bsum, nb);
    scan3<<<nb, 1024, 0, stream>>>(cnt, bsum, offs, N);

    fill_src<<<gE, 256, 0, stream>>>(row, col, rank, offs, srcb, E);

    // layer 1: xs = dis .* (x@W1) ; agg (dis fused at store)
    mm1<<<(N + 15) / 16, 256, 0, stream>>>(x, W1, dis, bufA, N);
    agg64<<<(N + 3) / 4, 256, 0, stream>>>(bufA, offs, srcb, dis, bufB, N);
    // layer 2: xs = dis .* (relu(agg1+b1)@W2) ; agg
    mm2<<<(N + 15) / 16, 256, 0, stream>>>(bufB, b1, W2, dis, bufA, N);
    agg64<<<(N + 3) / 4, 256, 0, stream>>>(bufA, offs, srcb, dis, bufB, N);
    // layer 3: xs = dis .* ((agg2+b2)@W3) ; agg (+b3) -> out
    mm3<<<(N + 63) / 64, 256, 0, stream>>>(bufB, b2, W3, dis, bufC, N);
    agg4<<<gN, 256, 0, stream>>>(bufC, offs, srcb, dis, b3, out, N);
}

// Round 4
// 620.941 us; speedup vs baseline: 1.3033x; 1.0567x over previous
//
#include <hip/hip_runtime.h>
#include <hip/hip_fp16.h>

#define IN_F 128
#define H 64

// ---------------- degree + per-edge rank (one atomic pass, 4 edges/thread) ----------------

__global__ void count_rank4(const int4* __restrict__ col4, int* __restrict__ cnt,
                            int* __restrict__ rank, int E4) {
    int e = blockIdx.x * 256 + threadIdx.x;
    if (e >= E4) return;
    int4 c = col4[e];
    int r0 = atomicAdd(&cnt[c.x], 1);
    int r1 = atomicAdd(&cnt[c.y], 1);
    int r2 = atomicAdd(&cnt[c.z], 1);
    int r3 = atomicAdd(&cnt[c.w], 1);
    int* rp = rank + (size_t)e * 4;
    __builtin_nontemporal_store(r0, rp);
    __builtin_nontemporal_store(r1, rp + 1);
    __builtin_nontemporal_store(r2, rp + 2);
    __builtin_nontemporal_store(r3, rp + 3);
}

__global__ void count_rank_tail(const int* __restrict__ col, int* __restrict__ cnt,
                                int* __restrict__ rank, int base, int E) {
    int e = base + blockIdx.x * 64 + threadIdx.x;
    if (e < E) rank[e] = atomicAdd(&cnt[col[e]], 1);
}

__global__ void calc_dis(const int* __restrict__ cnt, float* __restrict__ dis, int N) {
    int i = blockIdx.x * 256 + threadIdx.x;
    if (i < N) dis[i] = rsqrtf((float)(cnt[i] + 1));  // +1 self-loop; deg>=1 always
}

// ---------------- exclusive scan of cnt -> offs ----------------

__global__ void scan1(const int* __restrict__ cnt, int* __restrict__ bsum, int N) {
    __shared__ int s[1024];
    int t = threadIdx.x;
    int i = blockIdx.x * 1024 + t;
    s[t] = (i < N) ? cnt[i] : 0;
    __syncthreads();
    for (int off = 512; off > 0; off >>= 1) {
        if (t < off) s[t] += s[t + off];
        __syncthreads();
    }
    if (t == 0) bsum[blockIdx.x] = s[0];
}

__global__ void scan2(int* bsum, int nb) {
    __shared__ int s[128];
    int t = threadIdx.x;
    int v = (t < nb) ? bsum[t] : 0;
    s[t] = v;
    __syncthreads();
    for (int off = 1; off < 128; off <<= 1) {
        int tmp = (t >= off) ? s[t - off] : 0;
        __syncthreads();
        s[t] += tmp;
        __syncthreads();
    }
    if (t < nb) bsum[t] = s[t] - v;  // exclusive
}

__global__ void scan3(const int* __restrict__ cnt, const int* __restrict__ bsum,
                      int* __restrict__ offs, int N) {
    __shared__ int s[1024];
    int t = threadIdx.x;
    int i = blockIdx.x * 1024 + t;
    int v = (i < N) ? cnt[i] : 0;
    s[t] = v;
    __syncthreads();
    for (int off = 1; off < 1024; off <<= 1) {
        int tmp = (t >= off) ? s[t - off] : 0;
        __syncthreads();
        s[t] += tmp;
        __syncthreads();
    }
    if (i < N) offs[i] = bsum[blockIdx.x] + s[t] - v;       // exclusive prefix
    if (i == N - 1) offs[N] = bsum[blockIdx.x] + s[t];      // == E
}

// ---------------- CSR fill (col-sorted adjacency), atomic-free, 4 edges/thread -----------

__global__ void fill_src4(const int4* __restrict__ row4, const int4* __restrict__ col4,
                          const int4* __restrict__ rank4, const int* __restrict__ offs,
                          int* __restrict__ src, int E4) {
    int e = blockIdx.x * 256 + threadIdx.x;
    if (e >= E4) return;
    int4 r = row4[e];
    int4 c = col4[e];
    int4 k = rank4[e];
    __builtin_nontemporal_store(r.x, &src[offs[c.x] + k.x]);
    __builtin_nontemporal_store(r.y, &src[offs[c.y] + k.y]);
    __builtin_nontemporal_store(r.z, &src[offs[c.z] + k.z]);
    __builtin_nontemporal_store(r.w, &src[offs[c.w] + k.w]);
}

__global__ void fill_src_tail(const int* __restrict__ row, const int* __restrict__ col,
                              const int* __restrict__ rank, const int* __restrict__ offs,
                              int* __restrict__ src, int base, int E) {
    int e = base + blockIdx.x * 64 + threadIdx.x;
    if (e < E) src[offs[col[e]] + rank[e]] = row[e];
}

// ---------------- dense GEMMs (store pre-scaled by dis[r], fp16 out) ----------------

// out[r,:] = half( dis[r] * (x[r,:] @ W) )    x:[N,128] W:[128,64]
__global__ void mm1(const float* __restrict__ x, const float* __restrict__ W,
                    const float* __restrict__ dis, __half* __restrict__ out, int N) {
    __shared__ float Wl[IN_F * H];
    int t = threadIdx.x;
    for (int i = t; i < IN_F * H; i += 256) Wl[i] = W[i];
    __syncthreads();
    int c = t & 63, rq = t >> 6;
    int r0 = blockIdx.x * 16 + rq * 4;
    if (r0 >= N) return;
    float a0 = 0, a1 = 0, a2 = 0, a3 = 0;
    const float* x0 = x + (size_t)r0 * IN_F;
    for (int k = 0; k < IN_F; k += 4) {
        float4 v0 = *(const float4*)(x0 + k);
        float4 v1 = *(const float4*)(x0 + IN_F + k);
        float4 v2 = *(const float4*)(x0 + 2 * IN_F + k);
        float4 v3 = *(const float4*)(x0 + 3 * IN_F + k);
        float w0 = Wl[k * H + c], w1 = Wl[(k + 1) * H + c];
        float w2 = Wl[(k + 2) * H + c], w3 = Wl[(k + 3) * H + c];
        a0 += v0.x * w0 + v0.y * w1 + v0.z * w2 + v0.w * w3;
        a1 += v1.x * w0 + v1.y * w1 + v1.z * w2 + v1.w * w3;
        a2 += v2.x * w0 + v2.y * w1 + v2.z * w2 + v2.w * w3;
        a3 += v3.x * w0 + v3.y * w1 + v3.z * w2 + v3.w * w3;
    }
    __half* o = out + (size_t)r0 * H + c;
    o[0]     = __float2half(dis[r0]     * a0);
    o[H]     = __float2half(dis[r0 + 1] * a1);
    o[2 * H] = __float2half(dis[r0 + 2] * a2);
    o[3 * H] = __float2half(dis[r0 + 3] * a3);
}

// out[r,:] = half( dis[r] * (relu(hin[r,:] + b) @ W) )   hin f32
__global__ void mm2(const float* __restrict__ hin, const float* __restrict__ b,
                    const float* __restrict__ W, const float* __restrict__ dis,
                    __half* __restrict__ out, int N) {
    __shared__ float Wl[H * H];
    __shared__ float bl[H];
    int t = threadIdx.x;
    for (int i = t; i < H * H; i += 256) Wl[i] = W[i];
    if (t < H) bl[t] = b[t];
    __syncthreads();
    int c = t & 63, rq = t >> 6;
    int r0 = blockIdx.x * 16 + rq * 4;
    if (r0 >= N) return;
    float a0 = 0, a1 = 0, a2 = 0, a3 = 0;
    const float* h0 = hin + (size_t)r0 * H;
    for (int k = 0; k < H; k += 4) {
        float4 v0 = *(const float4*)(h0 + k);
        float4 v1 = *(const float4*)(h0 + H + k);
        float4 v2 = *(const float4*)(h0 + 2 * H + k);
        float4 v3 = *(const float4*)(h0 + 3 * H + k);
        float bb0 = bl[k], bb1 = bl[k + 1], bb2 = bl[k + 2], bb3 = bl[k + 3];
        v0.x = fmaxf(v0.x + bb0, 0.f); v0.y = fmaxf(v0.y + bb1, 0.f);
        v0.z = fmaxf(v0.z + bb2, 0.f); v0.w = fmaxf(v0.w + bb3, 0.f);
        v1.x = fmaxf(v1.x + bb0, 0.f); v1.y = fmaxf(v1.y + bb1, 0.f);
        v1.z = fmaxf(v1.z + bb2, 0.f); v1.w = fmaxf(v1.w + bb3, 0.f);
        v2.x = fmaxf(v2.x + bb0, 0.f); v2.y = fmaxf(v2.y + bb1, 0.f);
        v2.z = fmaxf(v2.z + bb2, 0.f); v2.w = fmaxf(v2.w + bb3, 0.f);
        v3.x = fmaxf(v3.x + bb0, 0.f); v3.y = fmaxf(v3.y + bb1, 0.f);
        v3.z = fmaxf(v3.z + bb2, 0.f); v3.w = fmaxf(v3.w + bb3, 0.f);
        float w0 = Wl[k * H + c], w1 = Wl[(k + 1) * H + c];
        float w2 = Wl[(k + 2) * H + c], w3 = Wl[(k + 3) * H + c];
        a0 += v0.x * w0 + v0.y * w1 + v0.z * w2 + v0.w * w3;
        a1 += v1.x * w0 + v1.y * w1 + v1.z * w2 + v1.w * w3;
        a2 += v2.x * w0 + v2.y * w1 + v2.z * w2 + v2.w * w3;
        a3 += v3.x * w0 + v3.y * w1 + v3.z * w2 + v3.w * w3;
    }
    __half* o = out + (size_t)r0 * H + c;
    o[0]     = __float2half(dis[r0]     * a0);
    o[H]     = __float2half(dis[r0 + 1] * a1);
    o[2 * H] = __float2half(dis[r0 + 2] * a2);
    o[3 * H] = __float2half(dis[r0 + 3] * a3);
}

// out[r,:] = dis[r] * ((hin[r,:] + b) @ W)   W:[64,4]  f32 in/out
__global__ void mm3(const float* __restrict__ hin, const float* __restrict__ b,
                    const float* __restrict__ W, const float* __restrict__ dis,
                    float* __restrict__ out, int N) {
    __shared__ float Wl[H * 4];
    __shared__ float bl[H];
    int t = threadIdx.x;
    if (t < H * 4) Wl[t] = W[t];
    if (t < H) bl[t] = b[t];
    __syncthreads();
    int c = t & 3, rr = t >> 2;
    int r = blockIdx.x * 64 + rr;
    if (r >= N) return;
    const float* h0 = hin + (size_t)r * H;
    float a = 0;
    for (int k = 0; k < H; k += 4) {
        float4 v = *(const float4*)(h0 + k);
        a += (v.x + bl[k])     * Wl[k * 4 + c];
        a += (v.y + bl[k + 1]) * Wl[(k + 1) * 4 + c];
        a += (v.z + bl[k + 2]) * Wl[(k + 2) * 4 + c];
        a += (v.w + bl[k + 3]) * Wl[(k + 3) * 4 + c];
    }
    out[(size_t)r * 4 + c] = dis[r] * a;
}

// ---------------- aggregation (gather over CSR) ----------------

// one wave per node, lane = feature. xs is fp16, accumulate f32, out f32.
// out[c,:] = dis[c] * (xs[c,:] + sum_src xs[src,:])
__global__ void agg64h(const __half* __restrict__ xs, const int* __restrict__ offs,
                       const int* __restrict__ src, const float* __restrict__ dis,
                       float* __restrict__ out, int N) {
    int wid = (blockIdx.x * 256 + threadIdx.x) >> 6;
    int lane = threadIdx.x & 63;
    if (wid >= N) return;
    int beg = offs[wid], end = offs[wid + 1];
    float acc = __half2float(xs[(size_t)wid * 64 + lane]);  // self-loop (pre-scaled)
    int j = beg;
    for (; j + 8 <= end; j += 8) {
        int s0 = src[j], s1 = src[j + 1], s2 = src[j + 2], s3 = src[j + 3];
        int s4 = src[j + 4], s5 = src[j + 5], s6 = src[j + 6], s7 = src[j + 7];
        float v0 = __half2float(xs[(size_t)s0 * 64 + lane]);
        float v1 = __half2float(xs[(size_t)s1 * 64 + lane]);
        float v2 = __half2float(xs[(size_t)s2 * 64 + lane]);
        float v3 = __half2float(xs[(size_t)s3 * 64 + lane]);
        float v4 = __half2float(xs[(size_t)s4 * 64 + lane]);
        float v5 = __half2float(xs[(size_t)s5 * 64 + lane]);
        float v6 = __half2float(xs[(size_t)s6 * 64 + lane]);
        float v7 = __half2float(xs[(size_t)s7 * 64 + lane]);
        acc += v0; acc += v1; acc += v2; acc += v3;
        acc += v4; acc += v5; acc += v6; acc += v7;
    }
    for (; j < end; ++j) acc += __half2float(xs[(size_t)src[j] * 64 + lane]);
    out[(size_t)wid * 64 + lane] = dis[wid] * acc;
}

// one thread per node, 4 features f32; writes final output: dis[c]*(inner) + b3
__global__ void agg4(const float* __restrict__ xs, const int* __restrict__ offs,
                     const int* __restrict__ src, const float* __restrict__ dis,
                     const float* __restrict__ b, float* __restrict__ out, int N) {
    int i = blockIdx.x * 256 + threadIdx.x;
    if (i >= N) return;
    float4 v = *(const float4*)(xs + (size_t)i * 4);
    float4 acc = v;  // self-loop term
    int beg = offs[i], end = offs[i + 1];
    for (int j = beg; j < end; ++j) {
        float4 m = *(const float4*)(xs + (size_t)src[j] * 4);
        acc.x += m.x; acc.y += m.y; acc.z += m.z; acc.w += m.w;
    }
    float d = dis[i];
    float4 o;
    o.x = b[0] + d * acc.x;
    o.y = b[1] + d * acc.y;
    o.z = b[2] + d * acc.z;
    o.w = b[3] + d * acc.w;
    *(float4*)(out + (size_t)i * 4) = o;
}

// ---------------- host ----------------

extern "C" void kernel_launch(void* const* d_in, const int* in_sizes, int n_in,
                              void* d_out, int out_size, void* d_ws, size_t ws_size,
                              hipStream_t stream) {
    const float* x  = (const float*)d_in[0];
    const int*   ei = (const int*)d_in[1];
    const float* W1 = (const float*)d_in[2];
    const float* b1 = (const float*)d_in[3];
    const float* W2 = (const float*)d_in[4];
    const float* b2 = (const float*)d_in[5];
    const float* W3 = (const float*)d_in[6];
    const float* b3 = (const float*)d_in[7];
    float* out = (float*)d_out;
    (void)n_in; (void)out_size; (void)ws_size;

    const int N = in_sizes[0] / IN_F;
    const int E = in_sizes[1] / 2;
    const int* row = ei;
    const int* col = ei + E;

    // workspace carve (all 256B-aligned)
    char* w = (char*)d_ws;
    auto carve = [&](size_t bytes) { char* p = w; w += (bytes + 255) & ~(size_t)255; return p; };
    __half* bufAh = (__half*)carve((size_t)N * H * 2);  // 12.8 MB (fp16 xs)
    float*  bufB  = (float*)carve((size_t)N * H * 4);   // 25.6 MB (agg out, f32)
    float*  bufC  = (float*)carve((size_t)N * 4 * 4);   // 1.6 MB
    float*  dis   = (float*)carve((size_t)N * 4);
    int*    cnt   = (int*)carve((size_t)N * 4);
    int*    offs  = (int*)carve((size_t)(N + 1) * 4);
    int*    bsum  = (int*)carve(4096);
    int*    rank  = (int*)carve((size_t)E * 4);         // 12.8 MB
    int*    srcb  = (int*)carve((size_t)E * 4);         // 12.8 MB

    (void)hipMemsetAsync(cnt, 0, (size_t)N * 4, stream);

    int E4 = E / 4;
    int tail = E - E4 * 4;
    int gN = (N + 255) / 256;
    int nb = (N + 1023) / 1024;  // 98 <= 128

    count_rank4<<<(E4 + 255) / 256, 256, 0, stream>>>((const int4*)col, cnt, rank, E4);
    if (tail)
        count_rank_tail<<<1, 64, 0, stream>>>(col, cnt, rank, E4 * 4, E);
    calc_dis<<<gN, 256, 0, stream>>>(cnt, dis, N);

    scan1<<<nb, 1024, 0, stream>>>(cnt, bsum, N);
    scan2<<<1, 128, 0, stream>>>(bsum, nb);
    scan3<<<nb, 1024, 0, stream>>>(cnt, bsum, offs, N);

    fill_src4<<<(E4 + 255) / 256, 256, 0, stream>>>((const int4*)row, (const int4*)col,
                                                    (const int4*)rank, offs, srcb, E4);
    if (tail)
        fill_src_tail<<<1, 64, 0, stream>>>(row, col, rank, offs, srcb, E4 * 4, E);

    // layer 1: xs = half(dis .* (x@W1)) ; agg -> f32
    mm1<<<(N + 15) / 16, 256, 0, stream>>>(x, W1, dis, bufAh, N);
    agg64h<<<(N + 3) / 4, 256, 0, stream>>>(bufAh, offs, srcb, dis, bufB, N);
    // layer 2: xs = half(dis .* (relu(agg1+b1)@W2)) ; agg -> f32
    mm2<<<(N + 15) / 16, 256, 0, stream>>>(bufB, b1, W2, dis, bufAh, N);
    agg64h<<<(N + 3) / 4, 256, 0, stream>>>(bufAh, offs, srcb, dis, bufB, N);
    // layer 3: xs = dis .* ((agg2+b2)@W3) ; agg (+b3) -> out   (f32 throughout)
    mm3<<<(N + 63) / 64, 256, 0, stream>>>(bufB, b2, W3, dis, bufC, N);
    agg4<<<gN, 256, 0, stream>>>(bufC, offs, srcb, dis, b3, out, N);
}

// Round 5
// 465.681 us; speedup vs baseline: 1.7378x; 1.3334x over previous
//
#include <hip/hip_runtime.h>
#include <hip/hip_fp16.h>

#define IN_F 128
#define H 64

#define BKT_BITS 8
#define BKT_SZ 256          // nodes per bucket
#define NBKT_MAX 512        // supports N <= 131072
#define CHUNK 8192          // edges per block in P1/P3

// ---------------- P1: per-bucket edge counts (LDS histogram) ----------------

__global__ void p1_bucket_count(const int* __restrict__ col, int* __restrict__ bucketCnt,
                                int E, int nbkt) {
    __shared__ int h[NBKT_MAX];
    int t = threadIdx.x;
    for (int i = t; i < NBKT_MAX; i += 256) h[i] = 0;
    __syncthreads();
    int beg = blockIdx.x * CHUNK;
    int end = min(E, beg + CHUNK);
    for (int j = beg + t; j < end; j += 256)
        atomicAdd(&h[col[j] >> BKT_BITS], 1);
    __syncthreads();
    for (int i = t; i < nbkt; i += 256)
        if (h[i]) atomicAdd(&bucketCnt[i], h[i]);
}

// ---------------- P2: scan bucket counts -> bases + cursors (1 block) ----------------

__global__ void p2_bucket_scan(const int* __restrict__ bucketCnt, int* __restrict__ base,
                               int* __restrict__ cursor, int nbkt) {
    __shared__ int s[NBKT_MAX];
    int t = threadIdx.x;  // 512 threads
    int v = (t < nbkt) ? bucketCnt[t] : 0;
    s[t] = v;
    __syncthreads();
    for (int off = 1; off < NBKT_MAX; off <<= 1) {
        int tmp = (t >= off) ? s[t - off] : 0;
        __syncthreads();
        s[t] += tmp;
        __syncthreads();
    }
    if (t < nbkt) {
        int b = s[t] - v;  // exclusive
        base[t] = b;
        cursor[t] = b;
    }
    if (t == nbkt - 1) base[nbkt] = s[t];  // == E
}

// ---------------- P3: partition edges into bucket-contiguous (row,col) ----------------

__global__ void p3_partition(const int* __restrict__ row, const int* __restrict__ col,
                             int* __restrict__ cursor, int2* __restrict__ part,
                             int E, int nbkt) {
    __shared__ int h[NBKT_MAX];
    __shared__ int res[NBKT_MAX];
    int t = threadIdx.x;
    for (int i = t; i < NBKT_MAX; i += 256) h[i] = 0;
    __syncthreads();
    int beg = blockIdx.x * CHUNK;
    int end = min(E, beg + CHUNK);
    for (int j = beg + t; j < end; j += 256)
        atomicAdd(&h[col[j] >> BKT_BITS], 1);
    __syncthreads();
    // one reservation atomic per (block, bucket)
    for (int i = t; i < nbkt; i += 256) {
        int c = h[i];
        res[i] = c ? atomicAdd(&cursor[i], c) : 0;
    }
    __syncthreads();
    for (int i = t; i < NBKT_MAX; i += 256) h[i] = 0;  // reuse as local cursor
    __syncthreads();
    for (int j = beg + t; j < end; j += 256) {
        int c = col[j];
        int b = c >> BKT_BITS;
        int l = atomicAdd(&h[b], 1);
        int2 pr; pr.x = row[j]; pr.y = c;
        part[res[b] + l] = pr;
    }
}

// ---------------- P4: per-bucket CSR finalize (offs, dis, src) ----------------

__global__ void p4_csr(const int2* __restrict__ part, const int* __restrict__ base,
                       int* __restrict__ offs, int* __restrict__ srcb,
                       float* __restrict__ dis, int N, int nbkt) {
    __shared__ int deg[BKT_SZ];
    __shared__ int lofs[BKT_SZ];
    __shared__ int cur[BKT_SZ];
    int b = blockIdx.x, t = threadIdx.x;  // 256 threads
    int eb = base[b], ee = base[b + 1];
    deg[t] = 0;
    __syncthreads();
    for (int j = eb + t; j < ee; j += 256)
        atomicAdd(&deg[part[j].y & (BKT_SZ - 1)], 1);
    __syncthreads();
    int v = deg[t];
    lofs[t] = v;
    __syncthreads();
    for (int off = 1; off < BKT_SZ; off <<= 1) {
        int tmp = (t >= off) ? lofs[t - off] : 0;
        __syncthreads();
        lofs[t] += tmp;
        __syncthreads();
    }
    int excl = lofs[t] - v;  // exclusive prefix within bucket
    int g = (b << BKT_BITS) + t;
    if (g < N) {
        offs[g] = eb + excl;
        dis[g] = rsqrtf((float)(v + 1));  // +1 self-loop
    }
    if (b == nbkt - 1 && t == 0) offs[N] = ee;  // == E
    deg[t] = excl;  // repurpose: scatter base per local node
    cur[t] = 0;
    __syncthreads();
    for (int j = eb + t; j < ee; j += 256) {
        int2 pr = part[j];
        int loc = pr.y & (BKT_SZ - 1);
        int l = atomicAdd(&cur[loc], 1);
        srcb[eb + deg[loc] + l] = pr.x;  // within-bucket region: L2 write-combined
    }
}

// ---------------- dense GEMMs (store pre-scaled by dis[r], fp16 out) ----------------

// out[r,:] = half( dis[r] * (x[r,:] @ W) )    x:[N,128] W:[128,64]
__global__ void mm1(const float* __restrict__ x, const float* __restrict__ W,
                    const float* __restrict__ dis, __half* __restrict__ out, int N) {
    __shared__ float Wl[IN_F * H];
    int t = threadIdx.x;
    for (int i = t; i < IN_F * H; i += 256) Wl[i] = W[i];
    __syncthreads();
    int c = t & 63, rq = t >> 6;
    int r0 = blockIdx.x * 16 + rq * 4;
    if (r0 >= N) return;
    float a0 = 0, a1 = 0, a2 = 0, a3 = 0;
    const float* x0 = x + (size_t)r0 * IN_F;
    for (int k = 0; k < IN_F; k += 4) {
        float4 v0 = *(const float4*)(x0 + k);
        float4 v1 = *(const float4*)(x0 + IN_F + k);
        float4 v2 = *(const float4*)(x0 + 2 * IN_F + k);
        float4 v3 = *(const float4*)(x0 + 3 * IN_F + k);
        float w0 = Wl[k * H + c], w1 = Wl[(k + 1) * H + c];
        float w2 = Wl[(k + 2) * H + c], w3 = Wl[(k + 3) * H + c];
        a0 += v0.x * w0 + v0.y * w1 + v0.z * w2 + v0.w * w3;
        a1 += v1.x * w0 + v1.y * w1 + v1.z * w2 + v1.w * w3;
        a2 += v2.x * w0 + v2.y * w1 + v2.z * w2 + v2.w * w3;
        a3 += v3.x * w0 + v3.y * w1 + v3.z * w2 + v3.w * w3;
    }
    __half* o = out + (size_t)r0 * H + c;
    o[0]     = __float2half(dis[r0]     * a0);
    o[H]     = __float2half(dis[r0 + 1] * a1);
    o[2 * H] = __float2half(dis[r0 + 2] * a2);
    o[3 * H] = __float2half(dis[r0 + 3] * a3);
}

// out[r,:] = half( dis[r] * (relu(hin[r,:] + b) @ W) )   hin f32
__global__ void mm2(const float* __restrict__ hin, const float* __restrict__ b,
                    const float* __restrict__ W, const float* __restrict__ dis,
                    __half* __restrict__ out, int N) {
    __shared__ float Wl[H * H];
    __shared__ float bl[H];
    int t = threadIdx.x;
    for (int i = t; i < H * H; i += 256) Wl[i] = W[i];
    if (t < H) bl[t] = b[t];
    __syncthreads();
    int c = t & 63, rq = t >> 6;
    int r0 = blockIdx.x * 16 + rq * 4;
    if (r0 >= N) return;
    float a0 = 0, a1 = 0, a2 = 0, a3 = 0;
    const float* h0 = hin + (size_t)r0 * H;
    for (int k = 0; k < H; k += 4) {
        float4 v0 = *(const float4*)(h0 + k);
        float4 v1 = *(const float4*)(h0 + H + k);
        float4 v2 = *(const float4*)(h0 + 2 * H + k);
        float4 v3 = *(const float4*)(h0 + 3 * H + k);
        float bb0 = bl[k], bb1 = bl[k + 1], bb2 = bl[k + 2], bb3 = bl[k + 3];
        v0.x = fmaxf(v0.x + bb0, 0.f); v0.y = fmaxf(v0.y + bb1, 0.f);
        v0.z = fmaxf(v0.z + bb2, 0.f); v0.w = fmaxf(v0.w + bb3, 0.f);
        v1.x = fmaxf(v1.x + bb0, 0.f); v1.y = fmaxf(v1.y + bb1, 0.f);
        v1.z = fmaxf(v1.z + bb2, 0.f); v1.w = fmaxf(v1.w + bb3, 0.f);
        v2.x = fmaxf(v2.x + bb0, 0.f); v2.y = fmaxf(v2.y + bb1, 0.f);
        v2.z = fmaxf(v2.z + bb2, 0.f); v2.w = fmaxf(v2.w + bb3, 0.f);
        v3.x = fmaxf(v3.x + bb0, 0.f); v3.y = fmaxf(v3.y + bb1, 0.f);
        v3.z = fmaxf(v3.z + bb2, 0.f); v3.w = fmaxf(v3.w + bb3, 0.f);
        float w0 = Wl[k * H + c], w1 = Wl[(k + 1) * H + c];
        float w2 = Wl[(k + 2) * H + c], w3 = Wl[(k + 3) * H + c];
        a0 += v0.x * w0 + v0.y * w1 + v0.z * w2 + v0.w * w3;
        a1 += v1.x * w0 + v1.y * w1 + v1.z * w2 + v1.w * w3;
        a2 += v2.x * w0 + v2.y * w1 + v2.z * w2 + v2.w * w3;
        a3 += v3.x * w0 + v3.y * w1 + v3.z * w2 + v3.w * w3;
    }
    __half* o = out + (size_t)r0 * H + c;
    o[0]     = __float2half(dis[r0]     * a0);
    o[H]     = __float2half(dis[r0 + 1] * a1);
    o[2 * H] = __float2half(dis[r0 + 2] * a2);
    o[3 * H] = __float2half(dis[r0 + 3] * a3);
}

// out[r,:] = dis[r] * ((hin[r,:] + b) @ W)   W:[64,4]  f32 in/out
__global__ void mm3(const float* __restrict__ hin, const float* __restrict__ b,
                    const float* __restrict__ W, const float* __restrict__ dis,
                    float* __restrict__ out, int N) {
    __shared__ float Wl[H * 4];
    __shared__ float bl[H];
    int t = threadIdx.x;
    if (t < H * 4) Wl[t] = W[t];
    if (t < H) bl[t] = b[t];
    __syncthreads();
    int c = t & 3, rr = t >> 2;
    int r = blockIdx.x * 64 + rr;
    if (r >= N) return;
    const float* h0 = hin + (size_t)r * H;
    float a = 0;
    for (int k = 0; k < H; k += 4) {
        float4 v = *(const float4*)(h0 + k);
        a += (v.x + bl[k])     * Wl[k * 4 + c];
        a += (v.y + bl[k + 1]) * Wl[(k + 1) * 4 + c];
        a += (v.z + bl[k + 2]) * Wl[(k + 2) * 4 + c];
        a += (v.w + bl[k + 3]) * Wl[(k + 3) * 4 + c];
    }
    out[(size_t)r * 4 + c] = dis[r] * a;
}

// ---------------- aggregation (gather over CSR) ----------------

// one wave per node, lane = feature. xs fp16, acc f32, out f32.
__global__ void agg64h(const __half* __restrict__ xs, const int* __restrict__ offs,
                       const int* __restrict__ src, const float* __restrict__ dis,
                       float* __restrict__ out, int N) {
    int wid = (blockIdx.x * 256 + threadIdx.x) >> 6;
    int lane = threadIdx.x & 63;
    if (wid >= N) return;
    int beg = offs[wid], end = offs[wid + 1];
    float acc = __half2float(xs[(size_t)wid * 64 + lane]);  // self-loop (pre-scaled)
    int j = beg;
    for (; j + 8 <= end; j += 8) {
        int s0 = src[j], s1 = src[j + 1], s2 = src[j + 2], s3 = src[j + 3];
        int s4 = src[j + 4], s5 = src[j + 5], s6 = src[j + 6], s7 = src[j + 7];
        float v0 = __half2float(xs[(size_t)s0 * 64 + lane]);
        float v1 = __half2float(xs[(size_t)s1 * 64 + lane]);
        float v2 = __half2float(xs[(size_t)s2 * 64 + lane]);
        float v3 = __half2float(xs[(size_t)s3 * 64 + lane]);
        float v4 = __half2float(xs[(size_t)s4 * 64 + lane]);
        float v5 = __half2float(xs[(size_t)s5 * 64 + lane]);
        float v6 = __half2float(xs[(size_t)s6 * 64 + lane]);
        float v7 = __half2float(xs[(size_t)s7 * 64 + lane]);
        acc += v0; acc += v1; acc += v2; acc += v3;
        acc += v4; acc += v5; acc += v6; acc += v7;
    }
    for (; j < end; ++j) acc += __half2float(xs[(size_t)src[j] * 64 + lane]);
    out[(size_t)wid * 64 + lane] = dis[wid] * acc;
}

// one thread per node, 4 features f32; final output: dis[c]*(inner) + b3
__global__ void agg4(const float* __restrict__ xs, const int* __restrict__ offs,
                     const int* __restrict__ src, const float* __restrict__ dis,
                     const float* __restrict__ b, float* __restrict__ out, int N) {
    int i = blockIdx.x * 256 + threadIdx.x;
    if (i >= N) return;
    float4 v = *(const float4*)(xs + (size_t)i * 4);
    float4 acc = v;  // self-loop term
    int beg = offs[i], end = offs[i + 1];
    for (int j = beg; j < end; ++j) {
        float4 m = *(const float4*)(xs + (size_t)src[j] * 4);
        acc.x += m.x; acc.y += m.y; acc.z += m.z; acc.w += m.w;
    }
    float d = dis[i];
    float4 o;
    o.x = b[0] + d * acc.x;
    o.y = b[1] + d * acc.y;
    o.z = b[2] + d * acc.z;
    o.w = b[3] + d * acc.w;
    *(float4*)(out + (size_t)i * 4) = o;
}

// ---------------- host ----------------

extern "C" void kernel_launch(void* const* d_in, const int* in_sizes, int n_in,
                              void* d_out, int out_size, void* d_ws, size_t ws_size,
                              hipStream_t stream) {
    const float* x  = (const float*)d_in[0];
    const int*   ei = (const int*)d_in[1];
    const float* W1 = (const float*)d_in[2];
    const float* b1 = (const float*)d_in[3];
    const float* W2 = (const float*)d_in[4];
    const float* b2 = (const float*)d_in[5];
    const float* W3 = (const float*)d_in[6];
    const float* b3 = (const float*)d_in[7];
    float* out = (float*)d_out;
    (void)n_in; (void)out_size; (void)ws_size;

    const int N = in_sizes[0] / IN_F;
    const int E = in_sizes[1] / 2;
    const int* row = ei;
    const int* col = ei + E;
    const int nbkt = (N + BKT_SZ - 1) >> BKT_BITS;  // 391 for N=100K (<= 512)

    // workspace carve (all 256B-aligned)
    char* w = (char*)d_ws;
    auto carve = [&](size_t bytes) { char* p = w; w += (bytes + 255) & ~(size_t)255; return p; };
    __half* bufAh  = (__half*)carve((size_t)N * H * 2);   // 12.8 MB (fp16 xs)
    float*  bufB   = (float*)carve((size_t)N * H * 4);    // 25.6 MB (agg out, f32)
    float*  bufC   = (float*)carve((size_t)N * 4 * 4);    // 1.6 MB
    float*  dis    = (float*)carve((size_t)N * 4);
    int*    offs   = (int*)carve((size_t)(N + 1) * 4);
    int*    srcb   = (int*)carve((size_t)E * 4);          // 12.8 MB
    int2*   part   = (int2*)carve((size_t)E * 8);         // 25.6 MB
    int*    bktCnt = (int*)carve((size_t)NBKT_MAX * 4);
    int*    bktBas = (int*)carve((size_t)(NBKT_MAX + 1) * 4);
    int*    bktCur = (int*)carve((size_t)NBKT_MAX * 4);

    (void)hipMemsetAsync(bktCnt, 0, (size_t)nbkt * 4, stream);

    int gE = (E + CHUNK - 1) / CHUNK;  // 391
    int gN = (N + 255) / 256;

    p1_bucket_count<<<gE, 256, 0, stream>>>(col, bktCnt, E, nbkt);
    p2_bucket_scan<<<1, NBKT_MAX, 0, stream>>>(bktCnt, bktBas, bktCur, nbkt);
    p3_partition<<<gE, 256, 0, stream>>>(row, col, bktCur, part, E, nbkt);
    p4_csr<<<nbkt, BKT_SZ, 0, stream>>>(part, bktBas, offs, srcb, dis, N, nbkt);

    // layer 1: xs = half(dis .* (x@W1)) ; agg -> f32
    mm1<<<(N + 15) / 16, 256, 0, stream>>>(x, W1, dis, bufAh, N);
    agg64h<<<(N + 3) / 4, 256, 0, stream>>>(bufAh, offs, srcb, dis, bufB, N);
    // layer 2: xs = half(dis .* (relu(agg1+b1)@W2)) ; agg -> f32
    mm2<<<(N + 15) / 16, 256, 0, stream>>>(bufB, b1, W2, dis, bufAh, N);
    agg64h<<<(N + 3) / 4, 256, 0, stream>>>(bufAh, offs, srcb, dis, bufB, N);
    // layer 3: xs = dis .* ((agg2+b2)@W3) ; agg (+b3) -> out   (f32 throughout)
    mm3<<<(N + 63) / 64, 256, 0, stream>>>(bufB, b2, W3, dis, bufC, N);
    agg4<<<gN, 256, 0, stream>>>(bufC, offs, srcb, dis, b3, out, N);
}